// Round 8
// baseline (2200.562 us; speedup 1.0000x reference)
//
#include <hip/hip_runtime.h>
#include <hip/hip_bf16.h>
#include <math.h>

#define D 64
#define RU 256
#define CHUNK 8
#define QSTRIDE 68

typedef short bf16x8 __attribute__((ext_vector_type(8)));
typedef float f32x4 __attribute__((ext_vector_type(4)));

__device__ __forceinline__ float selu_f(float x) {
    return x > 0.0f ? 1.0507009873554805f * x
                    : 1.7580993408473766f * (__expf(x) - 1.0f);
}

__device__ __forceinline__ short f2bf_rtne(float x) {
    union { float f; unsigned u; } v; v.f = x;
    unsigned r = (v.u + 0x7FFFu + ((v.u >> 16) & 1u)) >> 16;
    return (short)r;
}
__device__ __forceinline__ float bf2f(short s) {
    union { float f; unsigned u; } v; v.u = ((unsigned)(unsigned short)s) << 16;
    return v.f;
}

__device__ __forceinline__ bf16x8 pack8(const float* v) {
    union { bf16x8 v; unsigned u[4]; } H;
#pragma unroll
    for (int j = 0; j < 4; ++j) {
        float2 p; p.x = v[2 * j]; p.y = v[2 * j + 1];
        __hip_bfloat162 hb = __float22bfloat162_rn(p);
        H.u[j] = *(unsigned*)&hb;
    }
    return H.v;
}

__device__ __forceinline__ void split_pack8(const float* v, bf16x8* hi, bf16x8* lo) {
    union { bf16x8 v; unsigned u[4]; } H, L;
#pragma unroll
    for (int j = 0; j < 4; ++j) {
        float2 p; p.x = v[2 * j]; p.y = v[2 * j + 1];
        __hip_bfloat162 hb = __float22bfloat162_rn(p);
        unsigned hu = *(unsigned*)&hb;
        H.u[j] = hu;
        union { unsigned u; float f; } e, o;
        e.u = hu << 16;
        o.u = hu & 0xffff0000u;
        float2 q; q.x = p.x - e.f; q.y = p.y - o.f;
        __hip_bfloat162 lb = __float22bfloat162_rn(q);
        L.u[j] = *(unsigned*)&lb;
    }
    *hi = H.v; *lo = L.v;
}

// ---------------- CSR setup (once per launch) ----------------

__global__ __launch_bounds__(256) void hist2_kernel(
    const int* __restrict__ second, int* __restrict__ counts, int n_edges,
    const int* __restrict__ gid, int* __restrict__ gcounts, int n_links)
{
    const int t0 = blockIdx.x * blockDim.x + threadIdx.x;
    const int stride = gridDim.x * blockDim.x;
    for (int e = t0; e < n_edges; e += stride) atomicAdd(&counts[second[e]], 1);
    for (int l = t0; l < n_links; l += stride) atomicAdd(&gcounts[gid[l]], 1);
}

__global__ __launch_bounds__(1024) void scan_kernel(
    const int* __restrict__ counts, int* __restrict__ row_ptr,
    int* __restrict__ cursor, int n)
{
    __shared__ int wsum[16];
    __shared__ int woff[16];
    __shared__ int s_total;
    __shared__ int s_carry;
    const int tid = threadIdx.x, wave = tid >> 6, lane = tid & 63;
    if (tid == 0) s_carry = 0;
    __syncthreads();
    for (int base = 0; base < n; base += 1024) {
        const int i = base + tid;
        const int x = (i < n) ? counts[i] : 0;
        int v = x;
#pragma unroll
        for (int off = 1; off < 64; off <<= 1) {
            int t = __shfl_up(v, off, 64);
            if (lane >= off) v += t;
        }
        if (lane == 63) wsum[wave] = v;
        __syncthreads();
        if (wave == 0) {
            int s = (lane < 16) ? wsum[lane] : 0;
#pragma unroll
            for (int off = 1; off < 16; off <<= 1) {
                int t = __shfl_up(s, off, 64);
                if (lane >= off) s += t;
            }
            if (lane < 16) woff[lane] = s - wsum[lane];
            if (lane == 15) s_total = s;
        }
        __syncthreads();
        const int carry = s_carry;
        const int excl = carry + woff[wave] + (v - x);
        if (i < n) { row_ptr[i] = excl; if (cursor) cursor[i] = excl; }
        __syncthreads();
        if (tid == 0) s_carry += s_total;
        __syncthreads();
    }
    if (tid == 0) row_ptr[n] = s_carry;
}

__global__ __launch_bounds__(256) void scatter_kernel(
    const int* __restrict__ first, const int* __restrict__ second,
    int* __restrict__ cursor, int* __restrict__ sfirst, int n_edges)
{
    if (blockIdx.x == 0 && threadIdx.x < 64)
        sfirst[n_edges + threadIdx.x] = 0;        // pad for pipelined over-reads
    for (int e = blockIdx.x * blockDim.x + threadIdx.x; e < n_edges;
         e += gridDim.x * blockDim.x) {
        const int pos = atomicAdd(&cursor[second[e]], 1);
        sfirst[pos] = first[e];
    }
}

// ---------------- P via MFMA (split-bf16 compute, bf16 output) --------------
__global__ __launch_bounds__(256) void p_mfma_kernel(
    const float* __restrict__ state, const float* __restrict__ W_msg,
    unsigned short* __restrict__ P, int n_links)
{
    const int tid = threadIdx.x;
    const int wave = tid >> 6;
    const int lane = tid & 63;
    const int m = lane & 15;
    const int qd = lane >> 4;

    bf16x8 Bh[2][4], Bl[2][4];
#pragma unroll
    for (int ks = 0; ks < 2; ++ks)
#pragma unroll
        for (int jt = 0; jt < 4; ++jt) {
            const int nn = jt * 16 + m;
#pragma unroll
            for (int i = 0; i < 8; ++i) {
                const int kk = ks * 32 + qd * 8 + i;
                const float w = W_msg[kk * 64 + nn];
                const short hi = f2bf_rtne(w);
                Bh[ks][jt][i] = hi;
                Bl[ks][jt][i] = f2bf_rtne(w - bf2f(hi));
            }
        }

    const int ngroups = (n_links + 63) >> 6;
    for (int g = blockIdx.x; g < ngroups; g += gridDim.x) {
        const int base = g * 64 + wave * 16;
        const int l = base + m;
        const bool lv = (l < n_links);
        float xv[16];
        if (lv) {
            const float4* Sr = (const float4*)(state + (size_t)l * D);
            *(float4*)&xv[0]  = Sr[qd * 2];
            *(float4*)&xv[4]  = Sr[qd * 2 + 1];
            *(float4*)&xv[8]  = Sr[8 + qd * 2];
            *(float4*)&xv[12] = Sr[9 + qd * 2];
        } else {
#pragma unroll
            for (int i = 0; i < 16; ++i) xv[i] = 0.0f;
        }
        bf16x8 Ah[2], Al[2];
        split_pack8(&xv[0], &Ah[0], &Al[0]);
        split_pack8(&xv[8], &Ah[1], &Al[1]);
        f32x4 accP[4];
#pragma unroll
        for (int jt = 0; jt < 4; ++jt) {
            accP[jt] = (f32x4){0.f, 0.f, 0.f, 0.f};
#pragma unroll
            for (int ks = 0; ks < 2; ++ks) {
                accP[jt] = __builtin_amdgcn_mfma_f32_16x16x32_bf16(Ah[ks], Bh[ks][jt], accP[jt], 0, 0, 0);
                accP[jt] = __builtin_amdgcn_mfma_f32_16x16x32_bf16(Ah[ks], Bl[ks][jt], accP[jt], 0, 0, 0);
                accP[jt] = __builtin_amdgcn_mfma_f32_16x16x32_bf16(Al[ks], Bh[ks][jt], accP[jt], 0, 0, 0);
            }
        }
#pragma unroll
        for (int r = 0; r < 4; ++r) {
            const int lr = base + qd * 4 + r;
            if (lr < n_links) {
#pragma unroll
                for (int jt = 0; jt < 4; ++jt)
                    P[(size_t)lr * D + jt * 16 + m] =
                        (unsigned short)f2bf_rtne(accP[jt][r]);
            }
        }
    }
}

// ---------------- link-centric fused edge kernel, 3-stage pipeline ----------
__global__ __launch_bounds__(256, 5) void edge_link_kernel(
    const float* state, const unsigned short* __restrict__ P,
    const int* __restrict__ sfirst, const int* __restrict__ row_ptr,
    const float* __restrict__ b_msg, const float* __restrict__ W_msg,
    const float* __restrict__ W_gcn, const float* __restrict__ b_gcn,
    float* S, int n_links)
{
    __shared__ float qt[4][CHUNK * QSTRIDE + 4];
    const int tid = threadIdx.x;
    const int wave = tid >> 6;
    const int lane = tid & 63;
    const int m = lane & 15;
    const int qd = lane >> 4;

    const int l0 = (blockIdx.x * 4 + wave) * CHUNK;
    if (l0 >= n_links) return;
    const int l1 = min(l0 + CHUNK, n_links);
    const int nl = l1 - l0;

    float bmsgC[4];
#pragma unroll
    for (int jt = 0; jt < 4; ++jt) bmsgC[jt] = b_msg[jt * 16 + m];

    // ---- Phase 1: Q-tile (split-bf16, ks processed serially to cap VGPRs) --
    {
        const int l = l0 + m;
        const bool lv = (l < n_links) && (m < CHUNK);
        float xv[16];
        if (lv) {
            const float4* Sr = (const float4*)(state + (size_t)l * D);
            *(float4*)&xv[0]  = Sr[qd * 2];
            *(float4*)&xv[4]  = Sr[qd * 2 + 1];
            *(float4*)&xv[8]  = Sr[8 + qd * 2];
            *(float4*)&xv[12] = Sr[9 + qd * 2];
        } else {
#pragma unroll
            for (int i = 0; i < 16; ++i) xv[i] = 0.0f;
        }
        bf16x8 Ah[2], Al[2];
        split_pack8(&xv[0], &Ah[0], &Al[0]);
        split_pack8(&xv[8], &Ah[1], &Al[1]);
        f32x4 accQ[4];
#pragma unroll
        for (int jt = 0; jt < 4; ++jt) accQ[jt] = (f32x4){0.f, 0.f, 0.f, 0.f};
#pragma unroll
        for (int ks = 0; ks < 2; ++ks) {
            bf16x8 WbH[4], WbL[4];
#pragma unroll
            for (int jt = 0; jt < 4; ++jt) {
                const int nn = jt * 16 + m;
#pragma unroll
                for (int i = 0; i < 8; ++i) {
                    const int kk = 64 + ks * 32 + qd * 8 + i;
                    const float w = W_msg[kk * 64 + nn];
                    const short hi = f2bf_rtne(w);
                    WbH[jt][i] = hi;
                    WbL[jt][i] = f2bf_rtne(w - bf2f(hi));
                }
            }
#pragma unroll
            for (int jt = 0; jt < 4; ++jt) {
                accQ[jt] = __builtin_amdgcn_mfma_f32_16x16x32_bf16(Ah[ks], WbH[jt], accQ[jt], 0, 0, 0);
                accQ[jt] = __builtin_amdgcn_mfma_f32_16x16x32_bf16(Ah[ks], WbL[jt], accQ[jt], 0, 0, 0);
                accQ[jt] = __builtin_amdgcn_mfma_f32_16x16x32_bf16(Al[ks], WbH[jt], accQ[jt], 0, 0, 0);
            }
        }
#pragma unroll
        for (int r = 0; r < 4; ++r) {
            const int row = qd * 4 + r;
            if (row < CHUNK) {
#pragma unroll
                for (int jt = 0; jt < 4; ++jt)
                    qt[wave][row * QSTRIDE + jt * 16 + m] = accQ[jt][r] + bmsgC[jt];
            }
        }
    }

    // ---- W_gcn B-frags: plain bf16 ----
    bf16x8 Gh[2][4];
#pragma unroll
    for (int ks = 0; ks < 2; ++ks)
#pragma unroll
        for (int jt = 0; jt < 4; ++jt) {
            const int nn = jt * 16 + m;
#pragma unroll
            for (int i = 0; i < 8; ++i)
                Gh[ks][jt][i] = f2bf_rtne(W_gcn[(ks * 32 + qd * 8 + i) * 64 + nn]);
        }
    float bias_gcn[4], rb[4];
#pragma unroll
    for (int jt = 0; jt < 4; ++jt) {
        bias_gcn[jt] = b_gcn[jt * 16 + m];
        rb[jt] = fmaxf(bias_gcn[jt], 0.0f);
    }

    // ---- per-chunk row_ptr table in one lane-vector register ----
    const int rpv = row_ptr[l0 + min(lane, nl)];
#define RP(i) __shfl(rpv, (i), 64)

    // find first non-empty link (zeros for empties)
    int li0 = 0;
    while (li0 < nl && RP(li0 + 1) == RP(li0)) {
        S[(size_t)(l0 + li0) * D + lane] = 0.0f;
        ++li0;
    }
    if (li0 >= nl) return;
    int eo0 = RP(li0), ee0 = RP(li0 + 1);

    auto advance = [&](int& li, int& eo, int& ee, bool& v) {
        if (!v) return;
        eo += 16;
        if (eo < ee) return;
        int i = li + 1;
        while (i < nl) {
            const int a = RP(i), b = RP(i + 1);
            if (b > a) { li = i; eo = a; ee = b; return; }
            S[(size_t)(l0 + i) * D + lane] = 0.0f;   // empty link
            ++i;
        }
        v = false;
    };

    int li1 = li0, eo1 = eo0, ee1 = ee0; bool v1 = true;
    advance(li1, eo1, ee1, v1);
    int li2 = li1, eo2 = eo1, ee2 = ee1; bool v2 = v1;
    advance(li2, eo2, ee2, v2);

    // prologue loads (sfirst padded: over-reads are safe, values land in masked rows)
    const int sf0 = sfirst[eo0 + m];
    int sf1 = sfirst[eo1 + m];
    const unsigned short* Pr0 = P + (size_t)sf0 * D;
    bf16x8 p00 = *(const bf16x8*)(Pr0 + qd * 8);
    bf16x8 p01 = *(const bf16x8*)(Pr0 + 32 + qd * 8);

    float qb[16];
    int qli = -1;
    float rsum[4] = {0.f, 0.f, 0.f, 0.f};

    while (true) {
        // stage A: sfirst for tile t+2
        const int sf2 = sfirst[eo2 + m];
        // stage B: P rows for tile t+1 (sf1 loaded a full tile ago)
        const unsigned short* Pr1 = P + (size_t)sf1 * D;
        const bf16x8 p10 = *(const bf16x8*)(Pr1 + qd * 8);
        const bf16x8 p11 = *(const bf16x8*)(Pr1 + 32 + qd * 8);

        // stage C: compute tile t
        if (li0 != qli) {
            qli = li0;
            *(float4*)&qb[0]  = *(float4*)&qt[wave][li0 * QSTRIDE + qd * 8];
            *(float4*)&qb[4]  = *(float4*)&qt[wave][li0 * QSTRIDE + qd * 8 + 4];
            *(float4*)&qb[8]  = *(float4*)&qt[wave][li0 * QSTRIDE + 32 + qd * 8];
            *(float4*)&qb[12] = *(float4*)&qt[wave][li0 * QSTRIDE + 32 + qd * 8 + 4];
        }
        const bool ev = (eo0 + m < ee0);
        float msg[16];
#pragma unroll
        for (int i = 0; i < 8; ++i) {
            msg[i]     = ev ? selu_f(bf2f(p00[i]) + qb[i])     : 0.0f;
            msg[8 + i] = ev ? selu_f(bf2f(p01[i]) + qb[8 + i]) : 0.0f;
        }
        bf16x8 Ah0 = pack8(&msg[0]);
        bf16x8 Ah1 = pack8(&msg[8]);

        f32x4 acc[4];
#pragma unroll
        for (int jt = 0; jt < 4; ++jt) {
            const float b = bias_gcn[jt];
            acc[jt] = (f32x4){b, b, b, b};
            acc[jt] = __builtin_amdgcn_mfma_f32_16x16x32_bf16(Ah0, Gh[0][jt], acc[jt], 0, 0, 0);
            acc[jt] = __builtin_amdgcn_mfma_f32_16x16x32_bf16(Ah1, Gh[1][jt], acc[jt], 0, 0, 0);
        }
#pragma unroll
        for (int jt = 0; jt < 4; ++jt)
#pragma unroll
            for (int r = 0; r < 4; ++r)
                rsum[jt] += fmaxf(acc[jt][r], 0.0f);

        const int over = eo0 + qd * 4 + 4 - ee0;
        const float cnt = (float)max(0, min(4, over));
#pragma unroll
        for (int jt = 0; jt < 4; ++jt)
            rsum[jt] -= rb[jt] * cnt;

        if (eo0 + 16 >= ee0) {   // last tile of link li0
#pragma unroll
            for (int jt = 0; jt < 4; ++jt) {
                rsum[jt] += __shfl_xor(rsum[jt], 16, 64);
                rsum[jt] += __shfl_xor(rsum[jt], 32, 64);
            }
            const float outv = (qd == 0) ? rsum[0] : (qd == 1) ? rsum[1]
                             : (qd == 2) ? rsum[2] : rsum[3];
            S[(size_t)(l0 + li0) * D + lane] = outv;
#pragma unroll
            for (int jt = 0; jt < 4; ++jt) rsum[jt] = 0.0f;
        }

        if (!v1) break;
        li0 = li1; eo0 = eo1; ee0 = ee1;
        li1 = li2; eo1 = eo2; ee1 = ee2; v1 = v2;
        advance(li2, eo2, ee2, v2);
        p00 = p10; p01 = p11;
        sf1 = sf2;
    }
#undef RP
}

// ---------------- readout: parallel segment-sum + tiny MLP ----------------
__global__ __launch_bounds__(256) void gsum8_kernel(
    const float* __restrict__ S, const int* __restrict__ grow,
    float* __restrict__ gemb)
{
    __shared__ float red[4][64];
    const int g = blockIdx.x >> 3;
    const int slice = blockIdx.x & 7;
    const int slot = threadIdx.x >> 6;
    const int j = threadIdx.x & 63;
    const int ls = grow[g], le = grow[g + 1];
    float acc = 0.0f;
    for (int l = ls + slice * 4 + slot; l < le; l += 32)
        acc += S[(size_t)l * D + j];
    red[slot][j] = acc;
    __syncthreads();
    if (slot == 0)
        atomicAdd(&gemb[g * D + j], red[0][j] + red[1][j] + red[2][j] + red[3][j]);
}

__global__ __launch_bounds__(256) void mlp_kernel(
    const float* __restrict__ gemb,
    const float* __restrict__ W_r1, const float* __restrict__ b_r1,
    const float* __restrict__ W_r2, const float* __restrict__ b_r2,
    const float* __restrict__ W_r3, const float* __restrict__ b_r3,
    float* __restrict__ out)
{
    __shared__ float gl[64];
    __shared__ float row1[RU];
    __shared__ float row2[RU];
    __shared__ float fin[4];
    const int g = blockIdx.x;
    const int tid = threadIdx.x;
    const int slot = tid >> 6;
    const int lane = tid & 63;

    if (tid < 64) gl[tid] = gemb[g * D + tid];
    __syncthreads();

    float a1 = b_r1[tid];
#pragma unroll 8
    for (int k = 0; k < 64; ++k) a1 += gl[k] * W_r1[k * RU + tid];
    row1[tid] = selu_f(a1);
    __syncthreads();

    float a2 = b_r2[tid];
#pragma unroll 8
    for (int k = 0; k < RU; ++k) a2 += row1[k] * W_r2[k * RU + tid];
    row2[tid] = selu_f(a2);
    __syncthreads();

    float p = row2[tid] * W_r3[tid];
#pragma unroll
    for (int off = 32; off >= 1; off >>= 1)
        p += __shfl_down(p, off, 64);
    if (lane == 0) fin[slot] = p;
    __syncthreads();
    if (tid == 0)
        out[g] = fin[0] + fin[1] + fin[2] + fin[3] + b_r3[0];
}

extern "C" void kernel_launch(void* const* d_in, const int* in_sizes, int n_in,
                              void* d_out, int out_size, void* d_ws, size_t ws_size,
                              hipStream_t stream)
{
    const float* states_action = (const float*)d_in[0];
    const float* W_msg = (const float*)d_in[1];
    const float* b_msg = (const float*)d_in[2];
    const float* W_gcn = (const float*)d_in[3];
    const float* b_gcn = (const float*)d_in[4];
    const float* W_r1 = (const float*)d_in[5];
    const float* b_r1 = (const float*)d_in[6];
    const float* W_r2 = (const float*)d_in[7];
    const float* b_r2 = (const float*)d_in[8];
    const float* W_r3 = (const float*)d_in[9];
    const float* b_r3 = (const float*)d_in[10];
    const int* gid = (const int*)d_in[11];
    const int* first = (const int*)d_in[12];
    const int* second = (const int*)d_in[13];

    const int n_links = in_sizes[0] / D;     // 100000
    const int n_edges = in_sizes[12];        // 1600000
    const int G = out_size;                  // 256

    const size_t state_bytes = (size_t)n_links * D * sizeof(float);
    char* ws = (char*)d_ws;
    float* S = (float*)ws;                               // 25.6 MB
    unsigned short* Pb = (unsigned short*)(ws + state_bytes);   // 12.8 MB
    char* ws2 = ws + state_bytes + (size_t)n_links * D * sizeof(unsigned short);
    float* gemb = (float*)ws2;           ws2 += (size_t)G * D * sizeof(float);
    int* counts = (int*)ws2;             ws2 += (size_t)(n_links + 1) * sizeof(int);
    int* row_ptr = (int*)ws2;            ws2 += (size_t)(n_links + 1) * sizeof(int);
    int* cursor = (int*)ws2;             ws2 += (size_t)(n_links + 1) * sizeof(int);
    int* gcounts = (int*)ws2;            ws2 += (size_t)(G + 1) * sizeof(int);
    int* grow = (int*)ws2;               ws2 += (size_t)(G + 1) * sizeof(int);
    int* sfirst = (int*)ws2;             ws2 += (size_t)(n_edges + 64) * sizeof(int);

    // ---- CSR setup ----
    hipMemsetAsync(counts, 0, (size_t)(n_links + 1) * sizeof(int), stream);
    hipMemsetAsync(gcounts, 0, (size_t)(G + 1) * sizeof(int), stream);
    hipMemsetAsync(gemb, 0, (size_t)G * D * sizeof(float), stream);
    hist2_kernel<<<512, 256, 0, stream>>>(second, counts, n_edges, gid, gcounts, n_links);
    scan_kernel<<<1, 1024, 0, stream>>>(counts, row_ptr, cursor, n_links);
    scan_kernel<<<1, 1024, 0, stream>>>(gcounts, grow, (int*)nullptr, G);
    scatter_kernel<<<512, 256, 0, stream>>>(first, second, cursor, sfirst, n_edges);

    // ---- T = 4 message-passing iterations ----
    const int edge_blocks = (n_links + 4 * CHUNK - 1) / (4 * CHUNK);  // 3125
    const float* state_in = states_action;
    for (int t = 0; t < 4; ++t) {
        p_mfma_kernel<<<1563, 256, 0, stream>>>(state_in, W_msg, Pb, n_links);
        edge_link_kernel<<<edge_blocks, 256, 0, stream>>>(state_in, Pb, sfirst, row_ptr,
                                                          b_msg, W_msg, W_gcn, b_gcn,
                                                          S, n_links);
        state_in = S;
    }

    // ---- readout ----
    gsum8_kernel<<<G * 8, 256, 0, stream>>>(S, grow, gemb);
    mlp_kernel<<<G, 256, 0, stream>>>(gemb, W_r1, b_r1, W_r2, b_r2,
                                      W_r3, b_r3, (float*)d_out);
}

// Round 9
// 1091.294 us; speedup vs baseline: 2.0165x; 2.0165x over previous
//
#include <hip/hip_runtime.h>
#include <hip/hip_bf16.h>
#include <math.h>

#define D 64
#define RU 256
#define CHUNK 8
#define QSTRIDE 68

typedef short bf16x8 __attribute__((ext_vector_type(8)));
typedef float f32x4 __attribute__((ext_vector_type(4)));

__device__ __forceinline__ float selu_f(float x) {
    return x > 0.0f ? 1.0507009873554805f * x
                    : 1.7580993408473766f * (__expf(x) - 1.0f);
}

__device__ __forceinline__ short f2bf_rtne(float x) {
    union { float f; unsigned u; } v; v.f = x;
    unsigned r = (v.u + 0x7FFFu + ((v.u >> 16) & 1u)) >> 16;
    return (short)r;
}
__device__ __forceinline__ float bf2f(short s) {
    union { float f; unsigned u; } v; v.u = ((unsigned)(unsigned short)s) << 16;
    return v.f;
}

__device__ __forceinline__ bf16x8 pack8(const float* v) {
    union { bf16x8 v; unsigned u[4]; } H;
#pragma unroll
    for (int j = 0; j < 4; ++j) {
        float2 p; p.x = v[2 * j]; p.y = v[2 * j + 1];
        __hip_bfloat162 hb = __float22bfloat162_rn(p);
        H.u[j] = *(unsigned*)&hb;
    }
    return H.v;
}

__device__ __forceinline__ void split_pack8(const float* v, bf16x8* hi, bf16x8* lo) {
    union { bf16x8 v; unsigned u[4]; } H, L;
#pragma unroll
    for (int j = 0; j < 4; ++j) {
        float2 p; p.x = v[2 * j]; p.y = v[2 * j + 1];
        __hip_bfloat162 hb = __float22bfloat162_rn(p);
        unsigned hu = *(unsigned*)&hb;
        H.u[j] = hu;
        union { unsigned u; float f; } e, o;
        e.u = hu << 16;
        o.u = hu & 0xffff0000u;
        float2 q; q.x = p.x - e.f; q.y = p.y - o.f;
        __hip_bfloat162 lb = __float22bfloat162_rn(q);
        L.u[j] = *(unsigned*)&lb;
    }
    *hi = H.v; *lo = L.v;
}

// ---------------- CSR setup (once per launch) ----------------

__global__ __launch_bounds__(256) void hist2_kernel(
    const int* __restrict__ second, int* __restrict__ counts, int n_edges,
    const int* __restrict__ gid, int* __restrict__ gcounts, int n_links)
{
    const int t0 = blockIdx.x * blockDim.x + threadIdx.x;
    const int stride = gridDim.x * blockDim.x;
    for (int e = t0; e < n_edges; e += stride) atomicAdd(&counts[second[e]], 1);
    for (int l = t0; l < n_links; l += stride) atomicAdd(&gcounts[gid[l]], 1);
}

__global__ __launch_bounds__(1024) void scan_kernel(
    const int* __restrict__ counts, int* __restrict__ row_ptr,
    int* __restrict__ cursor, int n)
{
    __shared__ int wsum[16];
    __shared__ int woff[16];
    __shared__ int s_total;
    __shared__ int s_carry;
    const int tid = threadIdx.x, wave = tid >> 6, lane = tid & 63;
    if (tid == 0) s_carry = 0;
    __syncthreads();
    for (int base = 0; base < n; base += 1024) {
        const int i = base + tid;
        const int x = (i < n) ? counts[i] : 0;
        int v = x;
#pragma unroll
        for (int off = 1; off < 64; off <<= 1) {
            int t = __shfl_up(v, off, 64);
            if (lane >= off) v += t;
        }
        if (lane == 63) wsum[wave] = v;
        __syncthreads();
        if (wave == 0) {
            int s = (lane < 16) ? wsum[lane] : 0;
#pragma unroll
            for (int off = 1; off < 16; off <<= 1) {
                int t = __shfl_up(s, off, 64);
                if (lane >= off) s += t;
            }
            if (lane < 16) woff[lane] = s - wsum[lane];
            if (lane == 15) s_total = s;
        }
        __syncthreads();
        const int carry = s_carry;
        const int excl = carry + woff[wave] + (v - x);
        if (i < n) { row_ptr[i] = excl; if (cursor) cursor[i] = excl; }
        __syncthreads();
        if (tid == 0) s_carry += s_total;
        __syncthreads();
    }
    if (tid == 0) row_ptr[n] = s_carry;
}

__global__ __launch_bounds__(256) void scatter_kernel(
    const int* __restrict__ first, const int* __restrict__ second,
    int* __restrict__ cursor, int* __restrict__ sfirst, int n_edges)
{
    if (blockIdx.x == 0 && threadIdx.x < 64)
        sfirst[n_edges + threadIdx.x] = 0;        // pad for pipelined over-reads
    for (int e = blockIdx.x * blockDim.x + threadIdx.x; e < n_edges;
         e += gridDim.x * blockDim.x) {
        const int pos = atomicAdd(&cursor[second[e]], 1);
        sfirst[pos] = first[e];
    }
}

// ---------------- P via MFMA (split-bf16 compute, bf16 output) --------------
__global__ __launch_bounds__(256) void p_mfma_kernel(
    const float* __restrict__ state, const float* __restrict__ W_msg,
    unsigned short* __restrict__ P, int n_links)
{
    const int tid = threadIdx.x;
    const int wave = tid >> 6;
    const int lane = tid & 63;
    const int m = lane & 15;
    const int qd = lane >> 4;

    bf16x8 Bh[2][4], Bl[2][4];
#pragma unroll
    for (int ks = 0; ks < 2; ++ks)
#pragma unroll
        for (int jt = 0; jt < 4; ++jt) {
            const int nn = jt * 16 + m;
#pragma unroll
            for (int i = 0; i < 8; ++i) {
                const int kk = ks * 32 + qd * 8 + i;
                const float w = W_msg[kk * 64 + nn];
                const short hi = f2bf_rtne(w);
                Bh[ks][jt][i] = hi;
                Bl[ks][jt][i] = f2bf_rtne(w - bf2f(hi));
            }
        }

    const int ngroups = (n_links + 63) >> 6;
    for (int g = blockIdx.x; g < ngroups; g += gridDim.x) {
        const int base = g * 64 + wave * 16;
        const int l = base + m;
        const bool lv = (l < n_links);
        float xv[16];
        if (lv) {
            const float4* Sr = (const float4*)(state + (size_t)l * D);
            *(float4*)&xv[0]  = Sr[qd * 2];
            *(float4*)&xv[4]  = Sr[qd * 2 + 1];
            *(float4*)&xv[8]  = Sr[8 + qd * 2];
            *(float4*)&xv[12] = Sr[9 + qd * 2];
        } else {
#pragma unroll
            for (int i = 0; i < 16; ++i) xv[i] = 0.0f;
        }
        bf16x8 Ah[2], Al[2];
        split_pack8(&xv[0], &Ah[0], &Al[0]);
        split_pack8(&xv[8], &Ah[1], &Al[1]);
        f32x4 accP[4];
#pragma unroll
        for (int jt = 0; jt < 4; ++jt) {
            accP[jt] = (f32x4){0.f, 0.f, 0.f, 0.f};
#pragma unroll
            for (int ks = 0; ks < 2; ++ks) {
                accP[jt] = __builtin_amdgcn_mfma_f32_16x16x32_bf16(Ah[ks], Bh[ks][jt], accP[jt], 0, 0, 0);
                accP[jt] = __builtin_amdgcn_mfma_f32_16x16x32_bf16(Ah[ks], Bl[ks][jt], accP[jt], 0, 0, 0);
                accP[jt] = __builtin_amdgcn_mfma_f32_16x16x32_bf16(Al[ks], Bh[ks][jt], accP[jt], 0, 0, 0);
            }
        }
#pragma unroll
        for (int r = 0; r < 4; ++r) {
            const int lr = base + qd * 4 + r;
            if (lr < n_links) {
#pragma unroll
                for (int jt = 0; jt < 4; ++jt)
                    P[(size_t)lr * D + jt * 16 + m] =
                        (unsigned short)f2bf_rtne(accP[jt][r]);
            }
        }
    }
}

// ---------------- link-centric fused edge kernel, 3-stage pipeline ----------
// NOTE: no min-waves clause — round 8's (256,5) capped VGPRs at 48 and
// spilled ~1.3 GB/dispatch to scratch (FETCH 94MB->1GB). Compiler-chosen
// allocation (~110 VGPR, 4 waves/SIMD) is the right trade here.
__global__ __launch_bounds__(256) void edge_link_kernel(
    const float* state, const unsigned short* __restrict__ P,
    const int* __restrict__ sfirst, const int* __restrict__ row_ptr,
    const float* __restrict__ b_msg, const float* __restrict__ W_msg,
    const float* __restrict__ W_gcn, const float* __restrict__ b_gcn,
    float* S, int n_links)
{
    __shared__ float qt[4][CHUNK * QSTRIDE + 4];
    const int tid = threadIdx.x;
    const int wave = tid >> 6;
    const int lane = tid & 63;
    const int m = lane & 15;
    const int qd = lane >> 4;

    const int l0 = (blockIdx.x * 4 + wave) * CHUNK;
    if (l0 >= n_links) return;
    const int l1 = min(l0 + CHUNK, n_links);
    const int nl = l1 - l0;

    float bmsgC[4];
#pragma unroll
    for (int jt = 0; jt < 4; ++jt) bmsgC[jt] = b_msg[jt * 16 + m];

    // ---- Phase 1: Q-tile (split-bf16, ks processed serially to cap VGPRs) --
    {
        const int l = l0 + m;
        const bool lv = (l < n_links) && (m < CHUNK);
        float xv[16];
        if (lv) {
            const float4* Sr = (const float4*)(state + (size_t)l * D);
            *(float4*)&xv[0]  = Sr[qd * 2];
            *(float4*)&xv[4]  = Sr[qd * 2 + 1];
            *(float4*)&xv[8]  = Sr[8 + qd * 2];
            *(float4*)&xv[12] = Sr[9 + qd * 2];
        } else {
#pragma unroll
            for (int i = 0; i < 16; ++i) xv[i] = 0.0f;
        }
        bf16x8 Ah[2], Al[2];
        split_pack8(&xv[0], &Ah[0], &Al[0]);
        split_pack8(&xv[8], &Ah[1], &Al[1]);
        f32x4 accQ[4];
#pragma unroll
        for (int jt = 0; jt < 4; ++jt) accQ[jt] = (f32x4){0.f, 0.f, 0.f, 0.f};
#pragma unroll
        for (int ks = 0; ks < 2; ++ks) {
            bf16x8 WbH[4], WbL[4];
#pragma unroll
            for (int jt = 0; jt < 4; ++jt) {
                const int nn = jt * 16 + m;
#pragma unroll
                for (int i = 0; i < 8; ++i) {
                    const int kk = 64 + ks * 32 + qd * 8 + i;
                    const float w = W_msg[kk * 64 + nn];
                    const short hi = f2bf_rtne(w);
                    WbH[jt][i] = hi;
                    WbL[jt][i] = f2bf_rtne(w - bf2f(hi));
                }
            }
#pragma unroll
            for (int jt = 0; jt < 4; ++jt) {
                accQ[jt] = __builtin_amdgcn_mfma_f32_16x16x32_bf16(Ah[ks], WbH[jt], accQ[jt], 0, 0, 0);
                accQ[jt] = __builtin_amdgcn_mfma_f32_16x16x32_bf16(Ah[ks], WbL[jt], accQ[jt], 0, 0, 0);
                accQ[jt] = __builtin_amdgcn_mfma_f32_16x16x32_bf16(Al[ks], WbH[jt], accQ[jt], 0, 0, 0);
            }
        }
#pragma unroll
        for (int r = 0; r < 4; ++r) {
            const int row = qd * 4 + r;
            if (row < CHUNK) {
#pragma unroll
                for (int jt = 0; jt < 4; ++jt)
                    qt[wave][row * QSTRIDE + jt * 16 + m] = accQ[jt][r] + bmsgC[jt];
            }
        }
    }

    // ---- W_gcn B-frags: plain bf16 ----
    bf16x8 Gh[2][4];
#pragma unroll
    for (int ks = 0; ks < 2; ++ks)
#pragma unroll
        for (int jt = 0; jt < 4; ++jt) {
            const int nn = jt * 16 + m;
#pragma unroll
            for (int i = 0; i < 8; ++i)
                Gh[ks][jt][i] = f2bf_rtne(W_gcn[(ks * 32 + qd * 8 + i) * 64 + nn]);
        }
    float bias_gcn[4], rb[4];
#pragma unroll
    for (int jt = 0; jt < 4; ++jt) {
        bias_gcn[jt] = b_gcn[jt * 16 + m];
        rb[jt] = fmaxf(bias_gcn[jt], 0.0f);
    }

    // ---- per-chunk row_ptr table in one lane-vector register ----
    const int rpv = row_ptr[l0 + min(lane, nl)];
#define RP(i) __shfl(rpv, (i), 64)

    // find first non-empty link (zeros for empties)
    int li0 = 0;
    while (li0 < nl && RP(li0 + 1) == RP(li0)) {
        S[(size_t)(l0 + li0) * D + lane] = 0.0f;
        ++li0;
    }
    if (li0 >= nl) return;
    int eo0 = RP(li0), ee0 = RP(li0 + 1);

    auto advance = [&](int& li, int& eo, int& ee, bool& v) {
        if (!v) return;
        eo += 16;
        if (eo < ee) return;
        int i = li + 1;
        while (i < nl) {
            const int a = RP(i), b = RP(i + 1);
            if (b > a) { li = i; eo = a; ee = b; return; }
            S[(size_t)(l0 + i) * D + lane] = 0.0f;   // empty link
            ++i;
        }
        v = false;
    };

    int li1 = li0, eo1 = eo0, ee1 = ee0; bool v1 = true;
    advance(li1, eo1, ee1, v1);
    int li2 = li1, eo2 = eo1, ee2 = ee1; bool v2 = v1;
    advance(li2, eo2, ee2, v2);

    // prologue loads (sfirst padded: over-reads are safe, values land in masked rows)
    const int sf0 = sfirst[eo0 + m];
    int sf1 = sfirst[eo1 + m];
    const unsigned short* Pr0 = P + (size_t)sf0 * D;
    bf16x8 p00 = *(const bf16x8*)(Pr0 + qd * 8);
    bf16x8 p01 = *(const bf16x8*)(Pr0 + 32 + qd * 8);

    float qb[16];
    int qli = -1;
    float rsum[4] = {0.f, 0.f, 0.f, 0.f};

    while (true) {
        // stage A: sfirst for tile t+2
        const int sf2 = sfirst[eo2 + m];
        // stage B: P rows for tile t+1 (sf1 loaded a full tile ago)
        const unsigned short* Pr1 = P + (size_t)sf1 * D;
        const bf16x8 p10 = *(const bf16x8*)(Pr1 + qd * 8);
        const bf16x8 p11 = *(const bf16x8*)(Pr1 + 32 + qd * 8);

        // stage C: compute tile t
        if (li0 != qli) {
            qli = li0;
            *(float4*)&qb[0]  = *(float4*)&qt[wave][li0 * QSTRIDE + qd * 8];
            *(float4*)&qb[4]  = *(float4*)&qt[wave][li0 * QSTRIDE + qd * 8 + 4];
            *(float4*)&qb[8]  = *(float4*)&qt[wave][li0 * QSTRIDE + 32 + qd * 8];
            *(float4*)&qb[12] = *(float4*)&qt[wave][li0 * QSTRIDE + 32 + qd * 8 + 4];
        }
        const bool ev = (eo0 + m < ee0);
        float msg[16];
#pragma unroll
        for (int i = 0; i < 8; ++i) {
            msg[i]     = ev ? selu_f(bf2f(p00[i]) + qb[i])     : 0.0f;
            msg[8 + i] = ev ? selu_f(bf2f(p01[i]) + qb[8 + i]) : 0.0f;
        }
        bf16x8 Ah0 = pack8(&msg[0]);
        bf16x8 Ah1 = pack8(&msg[8]);

        f32x4 acc[4];
#pragma unroll
        for (int jt = 0; jt < 4; ++jt) {
            const float b = bias_gcn[jt];
            acc[jt] = (f32x4){b, b, b, b};
            acc[jt] = __builtin_amdgcn_mfma_f32_16x16x32_bf16(Ah0, Gh[0][jt], acc[jt], 0, 0, 0);
            acc[jt] = __builtin_amdgcn_mfma_f32_16x16x32_bf16(Ah1, Gh[1][jt], acc[jt], 0, 0, 0);
        }
#pragma unroll
        for (int jt = 0; jt < 4; ++jt)
#pragma unroll
            for (int r = 0; r < 4; ++r)
                rsum[jt] += fmaxf(acc[jt][r], 0.0f);

        const int over = eo0 + qd * 4 + 4 - ee0;
        const float cnt = (float)max(0, min(4, over));
#pragma unroll
        for (int jt = 0; jt < 4; ++jt)
            rsum[jt] -= rb[jt] * cnt;

        if (eo0 + 16 >= ee0) {   // last tile of link li0
#pragma unroll
            for (int jt = 0; jt < 4; ++jt) {
                rsum[jt] += __shfl_xor(rsum[jt], 16, 64);
                rsum[jt] += __shfl_xor(rsum[jt], 32, 64);
            }
            const float outv = (qd == 0) ? rsum[0] : (qd == 1) ? rsum[1]
                             : (qd == 2) ? rsum[2] : rsum[3];
            S[(size_t)(l0 + li0) * D + lane] = outv;
#pragma unroll
            for (int jt = 0; jt < 4; ++jt) rsum[jt] = 0.0f;
        }

        if (!v1) break;
        li0 = li1; eo0 = eo1; ee0 = ee1;
        li1 = li2; eo1 = eo2; ee1 = ee2; v1 = v2;
        advance(li2, eo2, ee2, v2);
        p00 = p10; p01 = p11;
        sf1 = sf2;
    }
#undef RP
}

// ---------------- readout: parallel segment-sum + tiny MLP ----------------
__global__ __launch_bounds__(256) void gsum8_kernel(
    const float* __restrict__ S, const int* __restrict__ grow,
    float* __restrict__ gemb)
{
    __shared__ float red[4][64];
    const int g = blockIdx.x >> 3;
    const int slice = blockIdx.x & 7;
    const int slot = threadIdx.x >> 6;
    const int j = threadIdx.x & 63;
    const int ls = grow[g], le = grow[g + 1];
    float acc = 0.0f;
    for (int l = ls + slice * 4 + slot; l < le; l += 32)
        acc += S[(size_t)l * D + j];
    red[slot][j] = acc;
    __syncthreads();
    if (slot == 0)
        atomicAdd(&gemb[g * D + j], red[0][j] + red[1][j] + red[2][j] + red[3][j]);
}

__global__ __launch_bounds__(256) void mlp_kernel(
    const float* __restrict__ gemb,
    const float* __restrict__ W_r1, const float* __restrict__ b_r1,
    const float* __restrict__ W_r2, const float* __restrict__ b_r2,
    const float* __restrict__ W_r3, const float* __restrict__ b_r3,
    float* __restrict__ out)
{
    __shared__ float gl[64];
    __shared__ float row1[RU];
    __shared__ float row2[RU];
    __shared__ float fin[4];
    const int g = blockIdx.x;
    const int tid = threadIdx.x;
    const int slot = tid >> 6;
    const int lane = tid & 63;

    if (tid < 64) gl[tid] = gemb[g * D + tid];
    __syncthreads();

    float a1 = b_r1[tid];
#pragma unroll 8
    for (int k = 0; k < 64; ++k) a1 += gl[k] * W_r1[k * RU + tid];
    row1[tid] = selu_f(a1);
    __syncthreads();

    float a2 = b_r2[tid];
#pragma unroll 8
    for (int k = 0; k < RU; ++k) a2 += row1[k] * W_r2[k * RU + tid];
    row2[tid] = selu_f(a2);
    __syncthreads();

    float p = row2[tid] * W_r3[tid];
#pragma unroll
    for (int off = 32; off >= 1; off >>= 1)
        p += __shfl_down(p, off, 64);
    if (lane == 0) fin[slot] = p;
    __syncthreads();
    if (tid == 0)
        out[g] = fin[0] + fin[1] + fin[2] + fin[3] + b_r3[0];
}

extern "C" void kernel_launch(void* const* d_in, const int* in_sizes, int n_in,
                              void* d_out, int out_size, void* d_ws, size_t ws_size,
                              hipStream_t stream)
{
    const float* states_action = (const float*)d_in[0];
    const float* W_msg = (const float*)d_in[1];
    const float* b_msg = (const float*)d_in[2];
    const float* W_gcn = (const float*)d_in[3];
    const float* b_gcn = (const float*)d_in[4];
    const float* W_r1 = (const float*)d_in[5];
    const float* b_r1 = (const float*)d_in[6];
    const float* W_r2 = (const float*)d_in[7];
    const float* b_r2 = (const float*)d_in[8];
    const float* W_r3 = (const float*)d_in[9];
    const float* b_r3 = (const float*)d_in[10];
    const int* gid = (const int*)d_in[11];
    const int* first = (const int*)d_in[12];
    const int* second = (const int*)d_in[13];

    const int n_links = in_sizes[0] / D;     // 100000
    const int n_edges = in_sizes[12];        // 1600000
    const int G = out_size;                  // 256

    const size_t state_bytes = (size_t)n_links * D * sizeof(float);
    char* ws = (char*)d_ws;
    float* S = (float*)ws;                               // 25.6 MB
    unsigned short* Pb = (unsigned short*)(ws + state_bytes);   // 12.8 MB
    char* ws2 = ws + state_bytes + (size_t)n_links * D * sizeof(unsigned short);
    float* gemb = (float*)ws2;           ws2 += (size_t)G * D * sizeof(float);
    int* counts = (int*)ws2;             ws2 += (size_t)(n_links + 1) * sizeof(int);
    int* row_ptr = (int*)ws2;            ws2 += (size_t)(n_links + 1) * sizeof(int);
    int* cursor = (int*)ws2;             ws2 += (size_t)(n_links + 1) * sizeof(int);
    int* gcounts = (int*)ws2;            ws2 += (size_t)(G + 1) * sizeof(int);
    int* grow = (int*)ws2;               ws2 += (size_t)(G + 1) * sizeof(int);
    int* sfirst = (int*)ws2;             ws2 += (size_t)(n_edges + 64) * sizeof(int);

    // ---- CSR setup ----
    hipMemsetAsync(counts, 0, (size_t)(n_links + 1) * sizeof(int), stream);
    hipMemsetAsync(gcounts, 0, (size_t)(G + 1) * sizeof(int), stream);
    hipMemsetAsync(gemb, 0, (size_t)G * D * sizeof(float), stream);
    hist2_kernel<<<512, 256, 0, stream>>>(second, counts, n_edges, gid, gcounts, n_links);
    scan_kernel<<<1, 1024, 0, stream>>>(counts, row_ptr, cursor, n_links);
    scan_kernel<<<1, 1024, 0, stream>>>(gcounts, grow, (int*)nullptr, G);
    scatter_kernel<<<512, 256, 0, stream>>>(first, second, cursor, sfirst, n_edges);

    // ---- T = 4 message-passing iterations ----
    const int edge_blocks = (n_links + 4 * CHUNK - 1) / (4 * CHUNK);  // 3125
    const float* state_in = states_action;
    for (int t = 0; t < 4; ++t) {
        p_mfma_kernel<<<1563, 256, 0, stream>>>(state_in, W_msg, Pb, n_links);
        edge_link_kernel<<<edge_blocks, 256, 0, stream>>>(state_in, Pb, sfirst, row_ptr,
                                                          b_msg, W_msg, W_gcn, b_gcn,
                                                          S, n_links);
        state_in = S;
    }

    // ---- readout ----
    gsum8_kernel<<<G * 8, 256, 0, stream>>>(S, grow, gemb);
    mlp_kernel<<<G, 256, 0, stream>>>(gemb, W_r1, b_r1, W_r2, b_r2,
                                      W_r3, b_r3, (float*)d_out);
}

// Round 10
// 1066.709 us; speedup vs baseline: 2.0629x; 1.0230x over previous
//
#include <hip/hip_runtime.h>
#include <hip/hip_bf16.h>
#include <math.h>

#define D 64
#define RU 256
#define CHUNK 8
#define QSTRIDE 68

typedef short bf16x8 __attribute__((ext_vector_type(8)));
typedef float f32x4 __attribute__((ext_vector_type(4)));

__device__ __forceinline__ float selu_f(float x) {
    return x > 0.0f ? 1.0507009873554805f * x
                    : 1.7580993408473766f * (__expf(x) - 1.0f);
}

__device__ __forceinline__ short f2bf_rtne(float x) {
    union { float f; unsigned u; } v; v.f = x;
    unsigned r = (v.u + 0x7FFFu + ((v.u >> 16) & 1u)) >> 16;
    return (short)r;
}
__device__ __forceinline__ float bf2f(short s) {
    union { float f; unsigned u; } v; v.u = ((unsigned)(unsigned short)s) << 16;
    return v.f;
}

__device__ __forceinline__ bf16x8 pack8(const float* v) {
    union { bf16x8 v; unsigned u[4]; } H;
#pragma unroll
    for (int j = 0; j < 4; ++j) {
        float2 p; p.x = v[2 * j]; p.y = v[2 * j + 1];
        __hip_bfloat162 hb = __float22bfloat162_rn(p);
        H.u[j] = *(unsigned*)&hb;
    }
    return H.v;
}

__device__ __forceinline__ void split_pack8(const float* v, bf16x8* hi, bf16x8* lo) {
    union { bf16x8 v; unsigned u[4]; } H, L;
#pragma unroll
    for (int j = 0; j < 4; ++j) {
        float2 p; p.x = v[2 * j]; p.y = v[2 * j + 1];
        __hip_bfloat162 hb = __float22bfloat162_rn(p);
        unsigned hu = *(unsigned*)&hb;
        H.u[j] = hu;
        union { unsigned u; float f; } e, o;
        e.u = hu << 16;
        o.u = hu & 0xffff0000u;
        float2 q; q.x = p.x - e.f; q.y = p.y - o.f;
        __hip_bfloat162 lb = __float22bfloat162_rn(q);
        L.u[j] = *(unsigned*)&lb;
    }
    *hi = H.v; *lo = L.v;
}

// ---------------- CSR setup (once per launch) ----------------
// Grid sized for ~8 waves/SIMD: atomic latency is hidden by TLP, not ILP.

__global__ __launch_bounds__(256) void hist2_kernel(
    const int* __restrict__ second, int* __restrict__ counts, int n_edges,
    const int* __restrict__ gid, int* __restrict__ gcounts, int n_links)
{
    const int t0 = blockIdx.x * blockDim.x + threadIdx.x;
    const int stride = gridDim.x * blockDim.x;
    for (int e = t0; e < n_edges; e += stride) atomicAdd(&counts[second[e]], 1);
    for (int l = t0; l < n_links; l += stride) atomicAdd(&gcounts[gid[l]], 1);
}

// exclusive scan, 4 elems/thread per iteration (25 barrier iters for 100K)
__global__ __launch_bounds__(1024) void scan_kernel(
    const int* __restrict__ counts, int* __restrict__ row_ptr,
    int* __restrict__ cursor, int n)
{
    __shared__ int wsum[16];
    __shared__ int woff[16];
    __shared__ int s_total;
    __shared__ int s_carry;
    const int tid = threadIdx.x, wave = tid >> 6, lane = tid & 63;
    if (tid == 0) s_carry = 0;
    __syncthreads();
    for (int base = 0; base < n; base += 4096) {
        const int i0 = base + tid * 4;
        int x0 = 0, x1 = 0, x2 = 0, x3 = 0;
        if (i0 + 3 < n) {
            const int4 x4 = *(const int4*)(counts + i0);
            x0 = x4.x; x1 = x4.y; x2 = x4.z; x3 = x4.w;
        } else {
            if (i0 < n) x0 = counts[i0];
            if (i0 + 1 < n) x1 = counts[i0 + 1];
            if (i0 + 2 < n) x2 = counts[i0 + 2];
            if (i0 + 3 < n) x3 = counts[i0 + 3];
        }
        const int tot = x0 + x1 + x2 + x3;
        int v = tot;
#pragma unroll
        for (int off = 1; off < 64; off <<= 1) {
            int t = __shfl_up(v, off, 64);
            if (lane >= off) v += t;
        }
        if (lane == 63) wsum[wave] = v;
        __syncthreads();
        if (wave == 0) {
            int s = (lane < 16) ? wsum[lane] : 0;
#pragma unroll
            for (int off = 1; off < 16; off <<= 1) {
                int t = __shfl_up(s, off, 64);
                if (lane >= off) s += t;
            }
            if (lane < 16) woff[lane] = s - wsum[lane];
            if (lane == 15) s_total = s;
        }
        __syncthreads();
        const int excl = s_carry + woff[wave] + (v - tot);
        int pre = excl;
        if (i0 < n)     { row_ptr[i0] = pre;     if (cursor) cursor[i0] = pre; }
        pre += x0;
        if (i0 + 1 < n) { row_ptr[i0 + 1] = pre; if (cursor) cursor[i0 + 1] = pre; }
        pre += x1;
        if (i0 + 2 < n) { row_ptr[i0 + 2] = pre; if (cursor) cursor[i0 + 2] = pre; }
        pre += x2;
        if (i0 + 3 < n) { row_ptr[i0 + 3] = pre; if (cursor) cursor[i0 + 3] = pre; }
        __syncthreads();
        if (tid == 0) s_carry += s_total;
        __syncthreads();
    }
    if (tid == 0) row_ptr[n] = s_carry;
}

__global__ __launch_bounds__(256) void scatter_kernel(
    const int* __restrict__ first, const int* __restrict__ second,
    int* __restrict__ cursor, int* __restrict__ sfirst, int n_edges)
{
    if (blockIdx.x == 0 && threadIdx.x < 64)
        sfirst[n_edges + threadIdx.x] = 0;        // pad for pipelined over-reads
    for (int e = blockIdx.x * blockDim.x + threadIdx.x; e < n_edges;
         e += gridDim.x * blockDim.x) {
        const int pos = atomicAdd(&cursor[second[e]], 1);
        sfirst[pos] = first[e];
    }
}

// ---------------- P via MFMA (split-bf16 compute, bf16 output) --------------
__global__ __launch_bounds__(256) void p_mfma_kernel(
    const float* __restrict__ state, const float* __restrict__ W_msg,
    unsigned short* __restrict__ P, int n_links)
{
    const int tid = threadIdx.x;
    const int wave = tid >> 6;
    const int lane = tid & 63;
    const int m = lane & 15;
    const int qd = lane >> 4;

    bf16x8 Bh[2][4], Bl[2][4];
#pragma unroll
    for (int ks = 0; ks < 2; ++ks)
#pragma unroll
        for (int jt = 0; jt < 4; ++jt) {
            const int nn = jt * 16 + m;
#pragma unroll
            for (int i = 0; i < 8; ++i) {
                const int kk = ks * 32 + qd * 8 + i;
                const float w = W_msg[kk * 64 + nn];
                const short hi = f2bf_rtne(w);
                Bh[ks][jt][i] = hi;
                Bl[ks][jt][i] = f2bf_rtne(w - bf2f(hi));
            }
        }

    const int ngroups = (n_links + 63) >> 6;
    for (int g = blockIdx.x; g < ngroups; g += gridDim.x) {
        const int base = g * 64 + wave * 16;
        const int l = base + m;
        const bool lv = (l < n_links);
        float xv[16];
        if (lv) {
            const float4* Sr = (const float4*)(state + (size_t)l * D);
            *(float4*)&xv[0]  = Sr[qd * 2];
            *(float4*)&xv[4]  = Sr[qd * 2 + 1];
            *(float4*)&xv[8]  = Sr[8 + qd * 2];
            *(float4*)&xv[12] = Sr[9 + qd * 2];
        } else {
#pragma unroll
            for (int i = 0; i < 16; ++i) xv[i] = 0.0f;
        }
        bf16x8 Ah[2], Al[2];
        split_pack8(&xv[0], &Ah[0], &Al[0]);
        split_pack8(&xv[8], &Ah[1], &Al[1]);
        f32x4 accP[4];
#pragma unroll
        for (int jt = 0; jt < 4; ++jt) {
            accP[jt] = (f32x4){0.f, 0.f, 0.f, 0.f};
#pragma unroll
            for (int ks = 0; ks < 2; ++ks) {
                accP[jt] = __builtin_amdgcn_mfma_f32_16x16x32_bf16(Ah[ks], Bh[ks][jt], accP[jt], 0, 0, 0);
                accP[jt] = __builtin_amdgcn_mfma_f32_16x16x32_bf16(Ah[ks], Bl[ks][jt], accP[jt], 0, 0, 0);
                accP[jt] = __builtin_amdgcn_mfma_f32_16x16x32_bf16(Al[ks], Bh[ks][jt], accP[jt], 0, 0, 0);
            }
        }
#pragma unroll
        for (int r = 0; r < 4; ++r) {
            const int lr = base + qd * 4 + r;
            if (lr < n_links) {
#pragma unroll
                for (int jt = 0; jt < 4; ++jt)
                    P[(size_t)lr * D + jt * 16 + m] =
                        (unsigned short)f2bf_rtne(accP[jt][r]);
            }
        }
    }
}

// ---------------- link-centric fused edge kernel, 3-stage pipeline ----------
// NOTE: no min-waves clause — round 8's (256,5) capped VGPRs at 48 and
// spilled ~1.3 GB/dispatch to scratch. Compiler-chosen allocation is right.
__global__ __launch_bounds__(256) void edge_link_kernel(
    const float* state, const unsigned short* __restrict__ P,
    const int* __restrict__ sfirst, const int* __restrict__ row_ptr,
    const float* __restrict__ b_msg, const float* __restrict__ W_msg,
    const float* __restrict__ W_gcn, const float* __restrict__ b_gcn,
    float* S, int n_links)
{
    __shared__ float qt[4][CHUNK * QSTRIDE + 4];
    const int tid = threadIdx.x;
    const int wave = tid >> 6;
    const int lane = tid & 63;
    const int m = lane & 15;
    const int qd = lane >> 4;

    const int l0 = (blockIdx.x * 4 + wave) * CHUNK;
    if (l0 >= n_links) return;
    const int l1 = min(l0 + CHUNK, n_links);
    const int nl = l1 - l0;

    float bmsgC[4];
#pragma unroll
    for (int jt = 0; jt < 4; ++jt) bmsgC[jt] = b_msg[jt * 16 + m];

    // ---- Phase 1: Q-tile (split-bf16, ks processed serially to cap VGPRs) --
    {
        const int l = l0 + m;
        const bool lv = (l < n_links) && (m < CHUNK);
        float xv[16];
        if (lv) {
            const float4* Sr = (const float4*)(state + (size_t)l * D);
            *(float4*)&xv[0]  = Sr[qd * 2];
            *(float4*)&xv[4]  = Sr[qd * 2 + 1];
            *(float4*)&xv[8]  = Sr[8 + qd * 2];
            *(float4*)&xv[12] = Sr[9 + qd * 2];
        } else {
#pragma unroll
            for (int i = 0; i < 16; ++i) xv[i] = 0.0f;
        }
        bf16x8 Ah[2], Al[2];
        split_pack8(&xv[0], &Ah[0], &Al[0]);
        split_pack8(&xv[8], &Ah[1], &Al[1]);
        f32x4 accQ[4];
#pragma unroll
        for (int jt = 0; jt < 4; ++jt) accQ[jt] = (f32x4){0.f, 0.f, 0.f, 0.f};
#pragma unroll
        for (int ks = 0; ks < 2; ++ks) {
            bf16x8 WbH[4], WbL[4];
#pragma unroll
            for (int jt = 0; jt < 4; ++jt) {
                const int nn = jt * 16 + m;
#pragma unroll
                for (int i = 0; i < 8; ++i) {
                    const int kk = 64 + ks * 32 + qd * 8 + i;
                    const float w = W_msg[kk * 64 + nn];
                    const short hi = f2bf_rtne(w);
                    WbH[jt][i] = hi;
                    WbL[jt][i] = f2bf_rtne(w - bf2f(hi));
                }
            }
#pragma unroll
            for (int jt = 0; jt < 4; ++jt) {
                accQ[jt] = __builtin_amdgcn_mfma_f32_16x16x32_bf16(Ah[ks], WbH[jt], accQ[jt], 0, 0, 0);
                accQ[jt] = __builtin_amdgcn_mfma_f32_16x16x32_bf16(Ah[ks], WbL[jt], accQ[jt], 0, 0, 0);
                accQ[jt] = __builtin_amdgcn_mfma_f32_16x16x32_bf16(Al[ks], WbH[jt], accQ[jt], 0, 0, 0);
            }
        }
#pragma unroll
        for (int r = 0; r < 4; ++r) {
            const int row = qd * 4 + r;
            if (row < CHUNK) {
#pragma unroll
                for (int jt = 0; jt < 4; ++jt)
                    qt[wave][row * QSTRIDE + jt * 16 + m] = accQ[jt][r] + bmsgC[jt];
            }
        }
    }

    // ---- W_gcn B-frags: plain bf16 ----
    bf16x8 Gh[2][4];
#pragma unroll
    for (int ks = 0; ks < 2; ++ks)
#pragma unroll
        for (int jt = 0; jt < 4; ++jt) {
            const int nn = jt * 16 + m;
#pragma unroll
            for (int i = 0; i < 8; ++i)
                Gh[ks][jt][i] = f2bf_rtne(W_gcn[(ks * 32 + qd * 8 + i) * 64 + nn]);
        }
    float bias_gcn[4], rb[4];
#pragma unroll
    for (int jt = 0; jt < 4; ++jt) {
        bias_gcn[jt] = b_gcn[jt * 16 + m];
        rb[jt] = fmaxf(bias_gcn[jt], 0.0f);
    }

    // ---- per-chunk row_ptr table in one lane-vector register ----
    const int rpv = row_ptr[l0 + min(lane, nl)];
#define RP(i) __shfl(rpv, (i), 64)

    int li0 = 0;
    while (li0 < nl && RP(li0 + 1) == RP(li0)) {
        S[(size_t)(l0 + li0) * D + lane] = 0.0f;
        ++li0;
    }
    if (li0 >= nl) return;
    int eo0 = RP(li0), ee0 = RP(li0 + 1);

    auto advance = [&](int& li, int& eo, int& ee, bool& v) {
        if (!v) return;
        eo += 16;
        if (eo < ee) return;
        int i = li + 1;
        while (i < nl) {
            const int a = RP(i), b = RP(i + 1);
            if (b > a) { li = i; eo = a; ee = b; return; }
            S[(size_t)(l0 + i) * D + lane] = 0.0f;   // empty link
            ++i;
        }
        v = false;
    };

    int li1 = li0, eo1 = eo0, ee1 = ee0; bool v1 = true;
    advance(li1, eo1, ee1, v1);
    int li2 = li1, eo2 = eo1, ee2 = ee1; bool v2 = v1;
    advance(li2, eo2, ee2, v2);

    const int sf0 = sfirst[eo0 + m];
    int sf1 = sfirst[eo1 + m];
    const unsigned short* Pr0 = P + (size_t)sf0 * D;
    bf16x8 p00 = *(const bf16x8*)(Pr0 + qd * 8);
    bf16x8 p01 = *(const bf16x8*)(Pr0 + 32 + qd * 8);

    float qb[16];
    int qli = -1;
    float rsum[4] = {0.f, 0.f, 0.f, 0.f};

    while (true) {
        const int sf2 = sfirst[eo2 + m];
        const unsigned short* Pr1 = P + (size_t)sf1 * D;
        const bf16x8 p10 = *(const bf16x8*)(Pr1 + qd * 8);
        const bf16x8 p11 = *(const bf16x8*)(Pr1 + 32 + qd * 8);

        if (li0 != qli) {
            qli = li0;
            *(float4*)&qb[0]  = *(float4*)&qt[wave][li0 * QSTRIDE + qd * 8];
            *(float4*)&qb[4]  = *(float4*)&qt[wave][li0 * QSTRIDE + qd * 8 + 4];
            *(float4*)&qb[8]  = *(float4*)&qt[wave][li0 * QSTRIDE + 32 + qd * 8];
            *(float4*)&qb[12] = *(float4*)&qt[wave][li0 * QSTRIDE + 32 + qd * 8 + 4];
        }
        const bool ev = (eo0 + m < ee0);
        float msg[16];
#pragma unroll
        for (int i = 0; i < 8; ++i) {
            msg[i]     = ev ? selu_f(bf2f(p00[i]) + qb[i])     : 0.0f;
            msg[8 + i] = ev ? selu_f(bf2f(p01[i]) + qb[8 + i]) : 0.0f;
        }
        bf16x8 Ah0 = pack8(&msg[0]);
        bf16x8 Ah1 = pack8(&msg[8]);

        f32x4 acc[4];
#pragma unroll
        for (int jt = 0; jt < 4; ++jt) {
            const float b = bias_gcn[jt];
            acc[jt] = (f32x4){b, b, b, b};
            acc[jt] = __builtin_amdgcn_mfma_f32_16x16x32_bf16(Ah0, Gh[0][jt], acc[jt], 0, 0, 0);
            acc[jt] = __builtin_amdgcn_mfma_f32_16x16x32_bf16(Ah1, Gh[1][jt], acc[jt], 0, 0, 0);
        }
#pragma unroll
        for (int jt = 0; jt < 4; ++jt)
#pragma unroll
            for (int r = 0; r < 4; ++r)
                rsum[jt] += fmaxf(acc[jt][r], 0.0f);

        const int over = eo0 + qd * 4 + 4 - ee0;
        const float cnt = (float)max(0, min(4, over));
#pragma unroll
        for (int jt = 0; jt < 4; ++jt)
            rsum[jt] -= rb[jt] * cnt;

        if (eo0 + 16 >= ee0) {   // last tile of link li0
#pragma unroll
            for (int jt = 0; jt < 4; ++jt) {
                rsum[jt] += __shfl_xor(rsum[jt], 16, 64);
                rsum[jt] += __shfl_xor(rsum[jt], 32, 64);
            }
            const float outv = (qd == 0) ? rsum[0] : (qd == 1) ? rsum[1]
                             : (qd == 2) ? rsum[2] : rsum[3];
            S[(size_t)(l0 + li0) * D + lane] = outv;
#pragma unroll
            for (int jt = 0; jt < 4; ++jt) rsum[jt] = 0.0f;
        }

        if (!v1) break;
        li0 = li1; eo0 = eo1; ee0 = ee1;
        li1 = li2; eo1 = eo2; ee1 = ee2; v1 = v2;
        advance(li2, eo2, ee2, v2);
        p00 = p10; p01 = p11;
        sf1 = sf2;
    }
#undef RP
}

// ---------------- readout: parallel segment-sum + tiny MLP ----------------
__global__ __launch_bounds__(256) void gsum8_kernel(
    const float* __restrict__ S, const int* __restrict__ grow,
    float* __restrict__ gemb)
{
    __shared__ float red[4][64];
    const int g = blockIdx.x >> 3;
    const int slice = blockIdx.x & 7;
    const int slot = threadIdx.x >> 6;
    const int j = threadIdx.x & 63;
    const int ls = grow[g], le = grow[g + 1];
    float acc = 0.0f;
    for (int l = ls + slice * 4 + slot; l < le; l += 32)
        acc += S[(size_t)l * D + j];
    red[slot][j] = acc;
    __syncthreads();
    if (slot == 0)
        atomicAdd(&gemb[g * D + j], red[0][j] + red[1][j] + red[2][j] + red[3][j]);
}

__global__ __launch_bounds__(256) void mlp_kernel(
    const float* __restrict__ gemb,
    const float* __restrict__ W_r1, const float* __restrict__ b_r1,
    const float* __restrict__ W_r2, const float* __restrict__ b_r2,
    const float* __restrict__ W_r3, const float* __restrict__ b_r3,
    float* __restrict__ out)
{
    __shared__ float gl[64];
    __shared__ float row1[RU];
    __shared__ float row2[RU];
    __shared__ float fin[4];
    const int g = blockIdx.x;
    const int tid = threadIdx.x;
    const int slot = tid >> 6;
    const int lane = tid & 63;

    if (tid < 64) gl[tid] = gemb[g * D + tid];
    __syncthreads();

    float a1 = b_r1[tid];
#pragma unroll 8
    for (int k = 0; k < 64; ++k) a1 += gl[k] * W_r1[k * RU + tid];
    row1[tid] = selu_f(a1);
    __syncthreads();

    float a2 = b_r2[tid];
#pragma unroll 8
    for (int k = 0; k < RU; ++k) a2 += row1[k] * W_r2[k * RU + tid];
    row2[tid] = selu_f(a2);
    __syncthreads();

    float p = row2[tid] * W_r3[tid];
#pragma unroll
    for (int off = 32; off >= 1; off >>= 1)
        p += __shfl_down(p, off, 64);
    if (lane == 0) fin[slot] = p;
    __syncthreads();
    if (tid == 0)
        out[g] = fin[0] + fin[1] + fin[2] + fin[3] + b_r3[0];
}

extern "C" void kernel_launch(void* const* d_in, const int* in_sizes, int n_in,
                              void* d_out, int out_size, void* d_ws, size_t ws_size,
                              hipStream_t stream)
{
    const float* states_action = (const float*)d_in[0];
    const float* W_msg = (const float*)d_in[1];
    const float* b_msg = (const float*)d_in[2];
    const float* W_gcn = (const float*)d_in[3];
    const float* b_gcn = (const float*)d_in[4];
    const float* W_r1 = (const float*)d_in[5];
    const float* b_r1 = (const float*)d_in[6];
    const float* W_r2 = (const float*)d_in[7];
    const float* b_r2 = (const float*)d_in[8];
    const float* W_r3 = (const float*)d_in[9];
    const float* b_r3 = (const float*)d_in[10];
    const int* gid = (const int*)d_in[11];
    const int* first = (const int*)d_in[12];
    const int* second = (const int*)d_in[13];

    const int n_links = in_sizes[0] / D;     // 100000
    const int n_edges = in_sizes[12];        // 1600000
    const int G = out_size;                  // 256

    const size_t state_bytes = (size_t)n_links * D * sizeof(float);
    char* ws = (char*)d_ws;
    float* S = (float*)ws;                               // 25.6 MB
    unsigned short* Pb = (unsigned short*)(ws + state_bytes);   // 12.8 MB
    char* ws2 = ws + state_bytes + (size_t)n_links * D * sizeof(unsigned short);
    float* gemb = (float*)ws2;           ws2 += (size_t)G * D * sizeof(float);
    int* counts = (int*)ws2;             ws2 += (size_t)(n_links + 1) * sizeof(int);
    int* row_ptr = (int*)ws2;            ws2 += (size_t)(n_links + 1) * sizeof(int);
    int* cursor = (int*)ws2;             ws2 += (size_t)(n_links + 1) * sizeof(int);
    int* gcounts = (int*)ws2;            ws2 += (size_t)(G + 1) * sizeof(int);
    int* grow = (int*)ws2;               ws2 += (size_t)(G + 1) * sizeof(int);
    int* sfirst = (int*)ws2;             ws2 += (size_t)(n_edges + 64) * sizeof(int);

    // ---- CSR setup (latency-bound atomics: big grids for wave-level hiding)
    hipMemsetAsync(counts, 0, (size_t)(n_links + 1) * sizeof(int), stream);
    hipMemsetAsync(gcounts, 0, (size_t)(G + 1) * sizeof(int), stream);
    hipMemsetAsync(gemb, 0, (size_t)G * D * sizeof(float), stream);
    hist2_kernel<<<4096, 256, 0, stream>>>(second, counts, n_edges, gid, gcounts, n_links);
    scan_kernel<<<1, 1024, 0, stream>>>(counts, row_ptr, cursor, n_links);
    scan_kernel<<<1, 1024, 0, stream>>>(gcounts, grow, (int*)nullptr, G);
    scatter_kernel<<<4096, 256, 0, stream>>>(first, second, cursor, sfirst, n_edges);

    // ---- T = 4 message-passing iterations ----
    const int edge_blocks = (n_links + 4 * CHUNK - 1) / (4 * CHUNK);  // 3125
    const float* state_in = states_action;
    for (int t = 0; t < 4; ++t) {
        p_mfma_kernel<<<782, 256, 0, stream>>>(state_in, W_msg, Pb, n_links);
        edge_link_kernel<<<edge_blocks, 256, 0, stream>>>(state_in, Pb, sfirst, row_ptr,
                                                          b_msg, W_msg, W_gcn, b_gcn,
                                                          S, n_links);
        state_in = S;
    }

    // ---- readout ----
    gsum8_kernel<<<G * 8, 256, 0, stream>>>(S, grow, gemb);
    mlp_kernel<<<G, 256, 0, stream>>>(gemb, W_r1, b_r1, W_r2, b_r2,
                                      W_r3, b_r3, (float*)d_out);
}

// Round 11
// 832.611 us; speedup vs baseline: 2.6430x; 1.2812x over previous
//
#include <hip/hip_runtime.h>
#include <hip/hip_bf16.h>
#include <math.h>

#define D 64
#define RU 256
#define CHUNK 8
#define QSTRIDE 68
#define BIN_SHIFT 7          // 128 links per coarse bin
#define NSB 256              // setup blocks for histA/scatterC

typedef short bf16x8 __attribute__((ext_vector_type(8)));
typedef float f32x4 __attribute__((ext_vector_type(4)));

__device__ __forceinline__ float selu_f(float x) {
    return x > 0.0f ? 1.0507009873554805f * x
                    : 1.7580993408473766f * (__expf(x) - 1.0f);
}

__device__ __forceinline__ short f2bf_rtne(float x) {
    union { float f; unsigned u; } v; v.f = x;
    unsigned r = (v.u + 0x7FFFu + ((v.u >> 16) & 1u)) >> 16;
    return (short)r;
}
__device__ __forceinline__ float bf2f(short s) {
    union { float f; unsigned u; } v; v.u = ((unsigned)(unsigned short)s) << 16;
    return v.f;
}

__device__ __forceinline__ bf16x8 pack8(const float* v) {
    union { bf16x8 v; unsigned u[4]; } H;
#pragma unroll
    for (int j = 0; j < 4; ++j) {
        float2 p; p.x = v[2 * j]; p.y = v[2 * j + 1];
        __hip_bfloat162 hb = __float22bfloat162_rn(p);
        H.u[j] = *(unsigned*)&hb;
    }
    return H.v;
}

__device__ __forceinline__ void split_pack8(const float* v, bf16x8* hi, bf16x8* lo) {
    union { bf16x8 v; unsigned u[4]; } H, L;
#pragma unroll
    for (int j = 0; j < 4; ++j) {
        float2 p; p.x = v[2 * j]; p.y = v[2 * j + 1];
        __hip_bfloat162 hb = __float22bfloat162_rn(p);
        unsigned hu = *(unsigned*)&hb;
        H.u[j] = hu;
        union { unsigned u; float f; } e, o;
        e.u = hu << 16;
        o.u = hu & 0xffff0000u;
        float2 q; q.x = p.x - e.f; q.y = p.y - o.f;
        __hip_bfloat162 lb = __float22bfloat162_rn(q);
        L.u[j] = *(unsigned*)&lb;
    }
    *hi = H.v; *lo = L.v;
}

// ================= atomic-free CSR build =================
// Global atomics run at a fixed ~8.5G/s on this part (occupancy-invariant,
// measured r10) — so the sort uses LDS atomics only.

// Pass A: per-block LDS histogram over coarse bins (second >> BIN_SHIFT).
__global__ __launch_bounds__(256) void histA_kernel(
    const int* __restrict__ second, int* __restrict__ ghist,
    int n_edges, int nbins)
{
    __shared__ int lhist[1024];
    for (int i = threadIdx.x; i < nbins; i += 256) lhist[i] = 0;
    __syncthreads();
    const int per = (n_edges + gridDim.x - 1) / gridDim.x;
    const int e0 = blockIdx.x * per;
    const int e1 = min(e0 + per, n_edges);
    for (int e = e0 + threadIdx.x; e < e1; e += 256)
        atomicAdd(&lhist[second[e] >> BIN_SHIFT], 1);
    __syncthreads();
    for (int i = threadIdx.x; i < nbins; i += 256)
        ghist[i * gridDim.x + blockIdx.x] = lhist[i];
}

// Pass B: single-block exclusive scan, 8 elems/thread, in place.
__global__ __launch_bounds__(1024) void scan8_kernel(int* __restrict__ data, int n)
{
    __shared__ int wsum[16], woff[16];
    __shared__ int s_total, s_carry;
    const int tid = threadIdx.x, wave = tid >> 6, lane = tid & 63;
    if (tid == 0) s_carry = 0;
    __syncthreads();
    for (int base = 0; base < n; base += 8192) {
        const int i0 = base + tid * 8;
        int x[8];
#pragma unroll
        for (int k = 0; k < 8; ++k) x[k] = 0;
        if (i0 + 8 <= n) {
            const int4 a = *(const int4*)(data + i0);
            const int4 b = *(const int4*)(data + i0 + 4);
            x[0] = a.x; x[1] = a.y; x[2] = a.z; x[3] = a.w;
            x[4] = b.x; x[5] = b.y; x[6] = b.z; x[7] = b.w;
        } else {
#pragma unroll
            for (int k = 0; k < 8; ++k) if (i0 + k < n) x[k] = data[i0 + k];
        }
        int tot = 0;
#pragma unroll
        for (int k = 0; k < 8; ++k) tot += x[k];
        int v = tot;
#pragma unroll
        for (int off = 1; off < 64; off <<= 1) {
            int t = __shfl_up(v, off, 64);
            if (lane >= off) v += t;
        }
        if (lane == 63) wsum[wave] = v;
        __syncthreads();
        if (wave == 0) {
            int s = (lane < 16) ? wsum[lane] : 0;
#pragma unroll
            for (int off = 1; off < 16; off <<= 1) {
                int t = __shfl_up(s, off, 64);
                if (lane >= off) s += t;
            }
            if (lane < 16) woff[lane] = s - wsum[lane];
            if (lane == 15) s_total = s;
        }
        __syncthreads();
        int pre = s_carry + woff[wave] + (v - tot);
#pragma unroll
        for (int k = 0; k < 8; ++k) {
            if (i0 + k < n) data[i0 + k] = pre;
            pre += x[k];
        }
        __syncthreads();
        if (tid == 0) s_carry += s_total;
        __syncthreads();
    }
}

// Pass C: deterministic scatter into bin-grouped tmp arrays (LDS cursors).
__global__ __launch_bounds__(256) void scatterC_kernel(
    const int* __restrict__ first, const int* __restrict__ second,
    const int* __restrict__ offs, int* __restrict__ tmp_first,
    int* __restrict__ tmp_sec, int n_edges, int nbins)
{
    __shared__ int lcur[1024];
    for (int i = threadIdx.x; i < nbins; i += 256)
        lcur[i] = offs[i * gridDim.x + blockIdx.x];
    __syncthreads();
    const int per = (n_edges + gridDim.x - 1) / gridDim.x;
    const int e0 = blockIdx.x * per;
    const int e1 = min(e0 + per, n_edges);
    for (int e = e0 + threadIdx.x; e < e1; e += 256) {
        const int s = second[e];
        const int pos = atomicAdd(&lcur[s >> BIN_SHIFT], 1);
        tmp_first[pos] = first[e];
        tmp_sec[pos] = s;
    }
}

// Pass D: per-bin counting sort (128 links/bin) -> row_ptr + sorted sfirst.
__global__ __launch_bounds__(256) void binsortD_kernel(
    const int* __restrict__ tmp_first, const int* __restrict__ tmp_sec,
    const int* __restrict__ offs, int* __restrict__ sfirst,
    int* __restrict__ row_ptr, int n_edges, int n_links, int nbins)
{
    __shared__ int ldeg[128];
    __shared__ int lpre[128];
    __shared__ int lcur[128];
    const int b = blockIdx.x;
    const int tid = threadIdx.x;
    const int lbase = b << BIN_SHIFT;
    const int nl = min(128, n_links - lbase);
    const int eb = offs[b * NSB];
    const int ee = (b + 1 < nbins) ? offs[(b + 1) * NSB] : n_edges;

    if (tid < 128) ldeg[tid] = 0;
    __syncthreads();
    for (int e = eb + tid; e < ee; e += 256)
        atomicAdd(&ldeg[tmp_sec[e] - lbase], 1);
    __syncthreads();
    if (tid < 64) {
        const int d0 = ldeg[tid], d1 = ldeg[64 + tid];
        int p0 = d0, p1 = d1;
#pragma unroll
        for (int off = 1; off < 64; off <<= 1) {
            const int t0 = __shfl_up(p0, off, 64);
            const int t1 = __shfl_up(p1, off, 64);
            if (tid >= off) { p0 += t0; p1 += t1; }
        }
        const int tot0 = __shfl(p0, 63, 64);
        lpre[tid] = p0 - d0;
        lpre[64 + tid] = tot0 + p1 - d1;
    }
    __syncthreads();
    if (tid < nl) row_ptr[lbase + tid] = eb + lpre[tid];
    if (b == nbins - 1 && tid == 0) row_ptr[n_links] = n_edges;
    if (tid < 128) lcur[tid] = lpre[tid];
    __syncthreads();
    for (int e = eb + tid; e < ee; e += 256) {
        const int pos = eb + atomicAdd(&lcur[tmp_sec[e] - lbase], 1);
        sfirst[pos] = tmp_first[e];
    }
    if (b == 0)
        for (int i = tid; i < 64; i += 256) sfirst[n_edges + i] = 0;  // pipeline pad
}

// grow via binary search (gid is sorted).
__global__ __launch_bounds__(256) void growfind_kernel(
    const int* __restrict__ gid, int* __restrict__ grow, int n_links, int G)
{
    const int g = blockIdx.x * blockDim.x + threadIdx.x;
    if (g > G) return;
    if (g == G) { grow[G] = n_links; return; }
    int lo = 0, hi = n_links;
    while (lo < hi) {
        const int mid = (lo + hi) >> 1;
        if (gid[mid] < g) lo = mid + 1; else hi = mid;
    }
    grow[g] = lo;
}

// ---------------- P via MFMA (split-bf16 compute, bf16 output) --------------
__global__ __launch_bounds__(256) void p_mfma_kernel(
    const float* __restrict__ state, const float* __restrict__ W_msg,
    unsigned short* __restrict__ P, int n_links)
{
    const int tid = threadIdx.x;
    const int wave = tid >> 6;
    const int lane = tid & 63;
    const int m = lane & 15;
    const int qd = lane >> 4;

    bf16x8 Bh[2][4], Bl[2][4];
#pragma unroll
    for (int ks = 0; ks < 2; ++ks)
#pragma unroll
        for (int jt = 0; jt < 4; ++jt) {
            const int nn = jt * 16 + m;
#pragma unroll
            for (int i = 0; i < 8; ++i) {
                const int kk = ks * 32 + qd * 8 + i;
                const float w = W_msg[kk * 64 + nn];
                const short hi = f2bf_rtne(w);
                Bh[ks][jt][i] = hi;
                Bl[ks][jt][i] = f2bf_rtne(w - bf2f(hi));
            }
        }

    const int ngroups = (n_links + 63) >> 6;
    for (int g = blockIdx.x; g < ngroups; g += gridDim.x) {
        const int base = g * 64 + wave * 16;
        const int l = base + m;
        const bool lv = (l < n_links);
        float xv[16];
        if (lv) {
            const float4* Sr = (const float4*)(state + (size_t)l * D);
            *(float4*)&xv[0]  = Sr[qd * 2];
            *(float4*)&xv[4]  = Sr[qd * 2 + 1];
            *(float4*)&xv[8]  = Sr[8 + qd * 2];
            *(float4*)&xv[12] = Sr[9 + qd * 2];
        } else {
#pragma unroll
            for (int i = 0; i < 16; ++i) xv[i] = 0.0f;
        }
        bf16x8 Ah[2], Al[2];
        split_pack8(&xv[0], &Ah[0], &Al[0]);
        split_pack8(&xv[8], &Ah[1], &Al[1]);
        f32x4 accP[4];
#pragma unroll
        for (int jt = 0; jt < 4; ++jt) {
            accP[jt] = (f32x4){0.f, 0.f, 0.f, 0.f};
#pragma unroll
            for (int ks = 0; ks < 2; ++ks) {
                accP[jt] = __builtin_amdgcn_mfma_f32_16x16x32_bf16(Ah[ks], Bh[ks][jt], accP[jt], 0, 0, 0);
                accP[jt] = __builtin_amdgcn_mfma_f32_16x16x32_bf16(Ah[ks], Bl[ks][jt], accP[jt], 0, 0, 0);
                accP[jt] = __builtin_amdgcn_mfma_f32_16x16x32_bf16(Al[ks], Bh[ks][jt], accP[jt], 0, 0, 0);
            }
        }
#pragma unroll
        for (int r = 0; r < 4; ++r) {
            const int lr = base + qd * 4 + r;
            if (lr < n_links) {
#pragma unroll
                for (int jt = 0; jt < 4; ++jt)
                    P[(size_t)lr * D + jt * 16 + m] =
                        (unsigned short)f2bf_rtne(accP[jt][r]);
            }
        }
    }
}

// ---------------- link-centric fused edge kernel, 3-stage pipeline ----------
// NOTE: no min-waves clause — (256,5) caused a full spill (r8).
__global__ __launch_bounds__(256) void edge_link_kernel(
    const float* state, const unsigned short* __restrict__ P,
    const int* __restrict__ sfirst, const int* __restrict__ row_ptr,
    const float* __restrict__ b_msg, const float* __restrict__ W_msg,
    const float* __restrict__ W_gcn, const float* __restrict__ b_gcn,
    float* S, int n_links)
{
    __shared__ float qt[4][CHUNK * QSTRIDE + 4];
    const int tid = threadIdx.x;
    const int wave = tid >> 6;
    const int lane = tid & 63;
    const int m = lane & 15;
    const int qd = lane >> 4;

    const int l0 = (blockIdx.x * 4 + wave) * CHUNK;
    if (l0 >= n_links) return;
    const int l1 = min(l0 + CHUNK, n_links);
    const int nl = l1 - l0;

    float bmsgC[4];
#pragma unroll
    for (int jt = 0; jt < 4; ++jt) bmsgC[jt] = b_msg[jt * 16 + m];

    // ---- Phase 1: Q-tile (split-bf16, ks serial to cap VGPRs) ----
    {
        const int l = l0 + m;
        const bool lv = (l < n_links) && (m < CHUNK);
        float xv[16];
        if (lv) {
            const float4* Sr = (const float4*)(state + (size_t)l * D);
            *(float4*)&xv[0]  = Sr[qd * 2];
            *(float4*)&xv[4]  = Sr[qd * 2 + 1];
            *(float4*)&xv[8]  = Sr[8 + qd * 2];
            *(float4*)&xv[12] = Sr[9 + qd * 2];
        } else {
#pragma unroll
            for (int i = 0; i < 16; ++i) xv[i] = 0.0f;
        }
        bf16x8 Ah[2], Al[2];
        split_pack8(&xv[0], &Ah[0], &Al[0]);
        split_pack8(&xv[8], &Ah[1], &Al[1]);
        f32x4 accQ[4];
#pragma unroll
        for (int jt = 0; jt < 4; ++jt) accQ[jt] = (f32x4){0.f, 0.f, 0.f, 0.f};
#pragma unroll
        for (int ks = 0; ks < 2; ++ks) {
            bf16x8 WbH[4], WbL[4];
#pragma unroll
            for (int jt = 0; jt < 4; ++jt) {
                const int nn = jt * 16 + m;
#pragma unroll
                for (int i = 0; i < 8; ++i) {
                    const int kk = 64 + ks * 32 + qd * 8 + i;
                    const float w = W_msg[kk * 64 + nn];
                    const short hi = f2bf_rtne(w);
                    WbH[jt][i] = hi;
                    WbL[jt][i] = f2bf_rtne(w - bf2f(hi));
                }
            }
#pragma unroll
            for (int jt = 0; jt < 4; ++jt) {
                accQ[jt] = __builtin_amdgcn_mfma_f32_16x16x32_bf16(Ah[ks], WbH[jt], accQ[jt], 0, 0, 0);
                accQ[jt] = __builtin_amdgcn_mfma_f32_16x16x32_bf16(Ah[ks], WbL[jt], accQ[jt], 0, 0, 0);
                accQ[jt] = __builtin_amdgcn_mfma_f32_16x16x32_bf16(Al[ks], WbH[jt], accQ[jt], 0, 0, 0);
            }
        }
#pragma unroll
        for (int r = 0; r < 4; ++r) {
            const int row = qd * 4 + r;
            if (row < CHUNK) {
#pragma unroll
                for (int jt = 0; jt < 4; ++jt)
                    qt[wave][row * QSTRIDE + jt * 16 + m] = accQ[jt][r] + bmsgC[jt];
            }
        }
    }

    // ---- W_gcn B-frags: plain bf16 ----
    bf16x8 Gh[2][4];
#pragma unroll
    for (int ks = 0; ks < 2; ++ks)
#pragma unroll
        for (int jt = 0; jt < 4; ++jt) {
            const int nn = jt * 16 + m;
#pragma unroll
            for (int i = 0; i < 8; ++i)
                Gh[ks][jt][i] = f2bf_rtne(W_gcn[(ks * 32 + qd * 8 + i) * 64 + nn]);
        }
    float bias_gcn[4], rb[4];
#pragma unroll
    for (int jt = 0; jt < 4; ++jt) {
        bias_gcn[jt] = b_gcn[jt * 16 + m];
        rb[jt] = fmaxf(bias_gcn[jt], 0.0f);
    }

    // ---- per-chunk row_ptr table in one lane-vector register ----
    const int rpv = row_ptr[l0 + min(lane, nl)];
#define RP(i) __shfl(rpv, (i), 64)

    int li0 = 0;
    while (li0 < nl && RP(li0 + 1) == RP(li0)) {
        S[(size_t)(l0 + li0) * D + lane] = 0.0f;
        ++li0;
    }
    if (li0 >= nl) return;
    int eo0 = RP(li0), ee0 = RP(li0 + 1);

    auto advance = [&](int& li, int& eo, int& ee, bool& v) {
        if (!v) return;
        eo += 16;
        if (eo < ee) return;
        int i = li + 1;
        while (i < nl) {
            const int a = RP(i), b = RP(i + 1);
            if (b > a) { li = i; eo = a; ee = b; return; }
            S[(size_t)(l0 + i) * D + lane] = 0.0f;   // empty link
            ++i;
        }
        v = false;
    };

    int li1 = li0, eo1 = eo0, ee1 = ee0; bool v1 = true;
    advance(li1, eo1, ee1, v1);
    int li2 = li1, eo2 = eo1, ee2 = ee1; bool v2 = v1;
    advance(li2, eo2, ee2, v2);

    const int sf0 = sfirst[eo0 + m];
    int sf1 = sfirst[eo1 + m];
    const unsigned short* Pr0 = P + (size_t)sf0 * D;
    bf16x8 p00 = *(const bf16x8*)(Pr0 + qd * 8);
    bf16x8 p01 = *(const bf16x8*)(Pr0 + 32 + qd * 8);

    float qb[16];
    int qli = -1;
    float rsum[4] = {0.f, 0.f, 0.f, 0.f};

    while (true) {
        const int sf2 = sfirst[eo2 + m];
        const unsigned short* Pr1 = P + (size_t)sf1 * D;
        const bf16x8 p10 = *(const bf16x8*)(Pr1 + qd * 8);
        const bf16x8 p11 = *(const bf16x8*)(Pr1 + 32 + qd * 8);

        if (li0 != qli) {
            qli = li0;
            *(float4*)&qb[0]  = *(float4*)&qt[wave][li0 * QSTRIDE + qd * 8];
            *(float4*)&qb[4]  = *(float4*)&qt[wave][li0 * QSTRIDE + qd * 8 + 4];
            *(float4*)&qb[8]  = *(float4*)&qt[wave][li0 * QSTRIDE + 32 + qd * 8];
            *(float4*)&qb[12] = *(float4*)&qt[wave][li0 * QSTRIDE + 32 + qd * 8 + 4];
        }
        const bool ev = (eo0 + m < ee0);
        float msg[16];
#pragma unroll
        for (int i = 0; i < 8; ++i) {
            msg[i]     = ev ? selu_f(bf2f(p00[i]) + qb[i])     : 0.0f;
            msg[8 + i] = ev ? selu_f(bf2f(p01[i]) + qb[8 + i]) : 0.0f;
        }
        bf16x8 Ah0 = pack8(&msg[0]);
        bf16x8 Ah1 = pack8(&msg[8]);

        f32x4 acc[4];
#pragma unroll
        for (int jt = 0; jt < 4; ++jt) {
            const float b = bias_gcn[jt];
            acc[jt] = (f32x4){b, b, b, b};
            acc[jt] = __builtin_amdgcn_mfma_f32_16x16x32_bf16(Ah0, Gh[0][jt], acc[jt], 0, 0, 0);
            acc[jt] = __builtin_amdgcn_mfma_f32_16x16x32_bf16(Ah1, Gh[1][jt], acc[jt], 0, 0, 0);
        }
#pragma unroll
        for (int jt = 0; jt < 4; ++jt)
#pragma unroll
            for (int r = 0; r < 4; ++r)
                rsum[jt] += fmaxf(acc[jt][r], 0.0f);

        const int over = eo0 + qd * 4 + 4 - ee0;
        const float cnt = (float)max(0, min(4, over));
#pragma unroll
        for (int jt = 0; jt < 4; ++jt)
            rsum[jt] -= rb[jt] * cnt;

        if (eo0 + 16 >= ee0) {   // last tile of link li0
#pragma unroll
            for (int jt = 0; jt < 4; ++jt) {
                rsum[jt] += __shfl_xor(rsum[jt], 16, 64);
                rsum[jt] += __shfl_xor(rsum[jt], 32, 64);
            }
            const float outv = (qd == 0) ? rsum[0] : (qd == 1) ? rsum[1]
                             : (qd == 2) ? rsum[2] : rsum[3];
            S[(size_t)(l0 + li0) * D + lane] = outv;
#pragma unroll
            for (int jt = 0; jt < 4; ++jt) rsum[jt] = 0.0f;
        }

        if (!v1) break;
        li0 = li1; eo0 = eo1; ee0 = ee1;
        li1 = li2; eo1 = eo2; ee1 = ee2; v1 = v2;
        advance(li2, eo2, ee2, v2);
        p00 = p10; p01 = p11;
        sf1 = sf2;
    }
#undef RP
}

// ---------------- readout: parallel segment-sum + tiny MLP ----------------
__global__ __launch_bounds__(256) void gsum8_kernel(
    const float* __restrict__ S, const int* __restrict__ grow,
    float* __restrict__ gemb)
{
    __shared__ float red[4][64];
    const int g = blockIdx.x >> 3;
    const int slice = blockIdx.x & 7;
    const int slot = threadIdx.x >> 6;
    const int j = threadIdx.x & 63;
    const int ls = grow[g], le = grow[g + 1];
    float acc = 0.0f;
    for (int l = ls + slice * 4 + slot; l < le; l += 32)
        acc += S[(size_t)l * D + j];
    red[slot][j] = acc;
    __syncthreads();
    if (slot == 0)
        atomicAdd(&gemb[g * D + j], red[0][j] + red[1][j] + red[2][j] + red[3][j]);
}

__global__ __launch_bounds__(256) void mlp_kernel(
    const float* __restrict__ gemb,
    const float* __restrict__ W_r1, const float* __restrict__ b_r1,
    const float* __restrict__ W_r2, const float* __restrict__ b_r2,
    const float* __restrict__ W_r3, const float* __restrict__ b_r3,
    float* __restrict__ out)
{
    __shared__ float gl[64];
    __shared__ float row1[RU];
    __shared__ float row2[RU];
    __shared__ float fin[4];
    const int g = blockIdx.x;
    const int tid = threadIdx.x;
    const int slot = tid >> 6;
    const int lane = tid & 63;

    if (tid < 64) gl[tid] = gemb[g * D + tid];
    __syncthreads();

    float a1 = b_r1[tid];
#pragma unroll 8
    for (int k = 0; k < 64; ++k) a1 += gl[k] * W_r1[k * RU + tid];
    row1[tid] = selu_f(a1);
    __syncthreads();

    float a2 = b_r2[tid];
#pragma unroll 8
    for (int k = 0; k < RU; ++k) a2 += row1[k] * W_r2[k * RU + tid];
    row2[tid] = selu_f(a2);
    __syncthreads();

    float p = row2[tid] * W_r3[tid];
#pragma unroll
    for (int off = 32; off >= 1; off >>= 1)
        p += __shfl_down(p, off, 64);
    if (lane == 0) fin[slot] = p;
    __syncthreads();
    if (tid == 0)
        out[g] = fin[0] + fin[1] + fin[2] + fin[3] + b_r3[0];
}

extern "C" void kernel_launch(void* const* d_in, const int* in_sizes, int n_in,
                              void* d_out, int out_size, void* d_ws, size_t ws_size,
                              hipStream_t stream)
{
    const float* states_action = (const float*)d_in[0];
    const float* W_msg = (const float*)d_in[1];
    const float* b_msg = (const float*)d_in[2];
    const float* W_gcn = (const float*)d_in[3];
    const float* b_gcn = (const float*)d_in[4];
    const float* W_r1 = (const float*)d_in[5];
    const float* b_r1 = (const float*)d_in[6];
    const float* W_r2 = (const float*)d_in[7];
    const float* b_r2 = (const float*)d_in[8];
    const float* W_r3 = (const float*)d_in[9];
    const float* b_r3 = (const float*)d_in[10];
    const int* gid = (const int*)d_in[11];
    const int* first = (const int*)d_in[12];
    const int* second = (const int*)d_in[13];

    const int n_links = in_sizes[0] / D;     // 100000
    const int n_edges = in_sizes[12];        // 1600000
    const int G = out_size;                  // 256
    const int nbins = (n_links + 127) >> BIN_SHIFT;   // 782 (<=1024 required)

    char* ws2 = (char*)d_ws;
    auto alloc = [&](size_t bytes) {
        char* p = ws2; ws2 += (bytes + 63) & ~(size_t)63; return p;
    };
    float* S = (float*)alloc((size_t)n_links * D * sizeof(float));        // 25.6 MB
    unsigned short* Pb = (unsigned short*)alloc((size_t)n_links * D * 2); // 12.8 MB
    float* gemb = (float*)alloc((size_t)G * D * sizeof(float));
    int* row_ptr = (int*)alloc((size_t)(n_links + 1) * sizeof(int));
    int* grow = (int*)alloc((size_t)(G + 1) * sizeof(int));
    int* ghist = (int*)alloc((size_t)nbins * NSB * sizeof(int));          // 0.8 MB
    int* tmp_first = (int*)alloc((size_t)n_edges * sizeof(int));          // 6.4 MB
    int* tmp_sec = (int*)alloc((size_t)n_edges * sizeof(int));            // 6.4 MB
    int* sfirst = (int*)alloc((size_t)(n_edges + 64) * sizeof(int));      // 6.4 MB

    // ---- atomic-free CSR build ----
    hipMemsetAsync(gemb, 0, (size_t)G * D * sizeof(float), stream);
    histA_kernel<<<NSB, 256, 0, stream>>>(second, ghist, n_edges, nbins);
    scan8_kernel<<<1, 1024, 0, stream>>>(ghist, nbins * NSB);
    scatterC_kernel<<<NSB, 256, 0, stream>>>(first, second, ghist,
                                             tmp_first, tmp_sec, n_edges, nbins);
    binsortD_kernel<<<nbins, 256, 0, stream>>>(tmp_first, tmp_sec, ghist,
                                               sfirst, row_ptr, n_edges, n_links, nbins);
    growfind_kernel<<<2, 256, 0, stream>>>(gid, grow, n_links, G);

    // ---- T = 4 message-passing iterations ----
    const int edge_blocks = (n_links + 4 * CHUNK - 1) / (4 * CHUNK);  // 3125
    const float* state_in = states_action;
    for (int t = 0; t < 4; ++t) {
        p_mfma_kernel<<<782, 256, 0, stream>>>(state_in, W_msg, Pb, n_links);
        edge_link_kernel<<<edge_blocks, 256, 0, stream>>>(state_in, Pb, sfirst, row_ptr,
                                                          b_msg, W_msg, W_gcn, b_gcn,
                                                          S, n_links);
        state_in = S;
    }

    // ---- readout ----
    gsum8_kernel<<<G * 8, 256, 0, stream>>>(S, grow, gemb);
    mlp_kernel<<<G, 256, 0, stream>>>(gemb, W_r1, b_r1, W_r2, b_r2,
                                      W_r3, b_r3, (float*)d_out);
}